// Round 6
// baseline (320.675 us; speedup 1.0000x reference)
//
#include <hip/hip_runtime.h>
#include <math.h>

namespace {
constexpr int SEQ = 2048;
constexpr int NH  = 16;
constexpr int DH  = 128;
constexpr int QB  = 64;          // q rows per block
constexpr int KBT = 64;          // k rows per iteration

typedef float f32x4 __attribute__((ext_vector_type(4)));
typedef short s16x8 __attribute__((ext_vector_type(8)));
typedef short s16x4 __attribute__((ext_vector_type(4)));
typedef unsigned short u16;

__device__ __forceinline__ u16 f2bf(float f) {
  unsigned u = __builtin_bit_cast(unsigned, f);
  return (u16)((u + 0x7fffu + ((u >> 16) & 1u)) >> 16);
}
__device__ __forceinline__ void gload16(const void* g, void* l) {
  __builtin_amdgcn_global_load_lds((const __attribute__((address_space(1))) void*)g,
                                   (__attribute__((address_space(3))) void*)l, 16, 0, 0);
}
}

// prep: K -> bf16 [b*8+hp][2h][k][128]; V -> bf16 transposed+k-pair-packed
// [b*8+hp][c=256][k']: per 32-k block, slot s (8 u16 at k'=s*8) holds
// k = {s*4+r} U {16+s*4+r}. One block per (b, head, ktile64). (unchanged)
__global__ __launch_bounds__(256) void prep_kernel(
    const float* __restrict__ kgl, const float* __restrict__ vg,
    u16* __restrict__ kb16, u16* __restrict__ vt16)
{
  __shared__ u16 vlds[64][132];
  const int tid = threadIdx.x, bid = blockIdx.x;
  const int kt = bid & 31, head = (bid >> 5) & 15, b = bid >> 9;
  const int k0 = kt * 64, hp = head >> 1, hh = head & 1;
  const float* ksrc = kgl + (((long)b*SEQ + k0)*NH + head)*DH;
  const float* vsrc = vg  + (((long)b*SEQ + k0)*NH + head)*DH;
  u16* kdst = kb16 + (((long)((b*8+hp)*2 + hh)*SEQ) + k0)*DH;
  #pragma unroll
  for (int i = 0; i < 8; ++i) {
    const int idx = tid + i*256, row = idx >> 5, c4 = idx & 31;
    const float4 v = *(const float4*)(ksrc + (long)row*(NH*DH) + c4*4);
    ushort4 pk = { f2bf(v.x), f2bf(v.y), f2bf(v.z), f2bf(v.w) };
    *(ushort4*)(kdst + row*DH + c4*4) = pk;
    const float4 w = *(const float4*)(vsrc + (long)row*(NH*DH) + c4*4);
    ushort4 pw = { f2bf(w.x), f2bf(w.y), f2bf(w.z), f2bf(w.w) };
    *(ushort4*)(&vlds[row][c4*4]) = pw;
  }
  __syncthreads();
  const int c = tid >> 1, half = tid & 1;
  u16* vdst = vt16 + (((long)(b*8+hp)*256) + hh*128 + c)*SEQ + k0 + half*32;
  #pragma unroll
  for (int j = 0; j < 8; ++j) {
    const int kb0 = (j >> 1)*4 + (j & 1)*16;
    ushort4 pk = { vlds[half*32 + kb0 + 0][c], vlds[half*32 + kb0 + 1][c],
                   vlds[half*32 + kb0 + 2][c], vlds[half*32 + kb0 + 3][c] };
    *(ushort4*)(vdst + j*4) = pk;
  }
}

// main: 256 blocks = (hp, b, p). Block runs qtile p then 31-p -> exactly
// 33 tile-iters (KBT=64) regardless of p: deterministic balance, 1 block/CU.
// 4 waves = (h, qw); wave holds 2 q-subtiles of 16 -> each V b128 feeds 4 MFMAs.
// LDS buf s @ s*65536: K [2h][64][256B] (chunk^=(row&7));
//                      V @+32768 [64 R][32 ch], ch=(khalf<<4)|(csub<<2)|(slot^(R&3)).
__global__ __launch_bounds__(256, 1) void diffattn_kernel(
    const float* __restrict__ qg,
    const u16* __restrict__ kb16, const u16* __restrict__ vt16,
    const float* __restrict__ lq1, const float* __restrict__ lk1,
    const float* __restrict__ lq2, const float* __restrict__ lk2,
    const float* __restrict__ wsub, const int* __restrict__ amask,
    float* __restrict__ outp, float lambda_init)
{
  __shared__ __align__(16) unsigned char smem[131072];
  const int tid = threadIdx.x, lane = tid & 63, wid = tid >> 6;
  const int h = wid >> 1, qw = wid & 1, lr = lane & 15, kb = lane >> 4;
  const int bid = blockIdx.x;
  const int hp = bid & 7, b = (bid >> 3) & 1, p = bid >> 4;   // p in 0..15

  float s1 = lq1[lane]*lk1[lane] + lq1[lane+64]*lk1[lane+64];
  float s2 = lq2[lane]*lk2[lane] + lq2[lane+64]*lk2[lane+64];
  #pragma unroll
  for (int o = 32; o; o >>= 1) { s1 += __shfl_xor(s1, o); s2 += __shfl_xor(s2, o); }
  const float lambda_full = expf(s1) - expf(s2) + lambda_init;

  // staging source offsets (u16 units); swizzle pre-applied to global source
  int koff[8], voff[8];
  #pragma unroll
  for (int i = 0; i < 8; ++i) {
    const int cid = tid + i*256;               // 0..2047 16B-chunks
    { const int hh = cid >> 10, row = (cid >> 4) & 63, ch = cid & 15;
      koff[i] = (hh*SEQ + row)*DH + (ch ^ (row & 7))*8; }
    { const int R = cid >> 5, ch = cid & 31;
      const int c = R*4 + ((ch >> 2) & 3), khalf = ch >> 4, sl = (ch & 3) ^ (R & 3);
      voff[i] = c*SEQ + khalf*32 + sl*8; }
  }
  const u16* kbB = kb16 + (long)(b*8+hp)*2*SEQ*DH;
  const u16* vtB = vt16 + (long)(b*8+hp)*256*SEQ;

  auto STAGE = [&](int k0s, int s) {
    unsigned char* dK = smem + s*65536;
    unsigned char* dV = dK + 32768;
    const u16* ksrc = kbB + (long)k0s*DH;
    const u16* vsrc = vtB + k0s;
    #pragma unroll
    for (int i = 0; i < 8; ++i) {
      gload16(ksrc + koff[i], dK + (tid + i*256)*16);
      gload16(vsrc + voff[i], dV + (tid + i*256)*16);
    }
  };

  const float qscale = 1.44269504088896f / sqrtf((float)DH);
  const int vof0 = ((lr >> 2) << 9) + ((lr & 3) << 6) + ((kb ^ (lr >> 2)) << 4);
  const int swk = (lr & 7) << 4;

  #pragma unroll 1
  for (int qi = 0; qi < 2; ++qi) {
    const int qtile = qi ? (31 - p) : p;
    const int q0 = qtile * QB;
    __syncthreads();                 // prior epilogue LDS reads done

    s16x8 qf[2][4];
    #pragma unroll
    for (int qs = 0; qs < 2; ++qs) {
      const int qrow = q0 + qw*32 + qs*16 + lr;
      const float* qp = qg + (((long)b*SEQ + qrow)*NH + hp*2 + h)*DH;
      #pragma unroll
      for (int ds = 0; ds < 4; ++ds) {
        const float4 a0 = *(const float4*)(qp + ds*32 + kb*8);
        const float4 a1 = *(const float4*)(qp + ds*32 + kb*8 + 4);
        s16x8 f;
        f[0]=(short)f2bf(a0.x*qscale); f[1]=(short)f2bf(a0.y*qscale);
        f[2]=(short)f2bf(a0.z*qscale); f[3]=(short)f2bf(a0.w*qscale);
        f[4]=(short)f2bf(a1.x*qscale); f[5]=(short)f2bf(a1.y*qscale);
        f[6]=(short)f2bf(a1.z*qscale); f[7]=(short)f2bf(a1.w*qscale);
        qf[qs][ds] = f;
      }
    }

    f32x4 acc[2][16];
    #pragma unroll
    for (int qs = 0; qs < 2; ++qs)
      #pragma unroll
      for (int i = 0; i < 16; ++i) acc[qs][i] = (f32x4){0.f,0.f,0.f,0.f};
    float m_run[2] = {-3.0e38f, -3.0e38f}, l_run[2] = {0.f, 0.f};
    const int nt = qtile + 1;

    STAGE(0, 0);
    __syncthreads();                 // buf0 ready (barrier drains vmcnt)

    for (int t = 0; t < nt; ++t) {
      const int cur = t & 1;
      if (t + 1 < nt) STAGE((t+1)*KBT, cur ^ 1);    // async prefetch
      const int k0 = t * KBT;

      // 64-bit key mask, issued early so latency hides under QK
      const int mi = amask[b*SEQ + k0 + lane];
      const unsigned long long bm64 = __ballot(mi != 0);

      // S^T = K . Q^T (16x16x32); af reused across both q-subtiles
      const unsigned char* Kc = smem + cur*65536 + h*16384;
      f32x4 st[2][4];
      #pragma unroll
      for (int kt2 = 0; kt2 < 4; ++kt2) {
        const unsigned char* kr = Kc + (kt2*16 + lr)*256;
        f32x4 c0 = {0.f,0.f,0.f,0.f}, c1 = {0.f,0.f,0.f,0.f};
        #pragma unroll
        for (int ds = 0; ds < 4; ++ds) {
          const s16x8 af = *(const s16x8*)(kr + ((ds*64 + kb*16) ^ swk));
          c0 = __builtin_amdgcn_mfma_f32_16x16x32_bf16(af, qf[0][ds], c0, 0, 0, 0);
          c1 = __builtin_amdgcn_mfma_f32_16x16x32_bf16(af, qf[1][ds], c1, 0, 0, 0);
        }
        st[0][kt2] = c0; st[1][kt2] = c1;
      }

      // online softmax per q-subtile (exp2 domain); lane owns q-row lr
      float fac[2], pp[2][4][4];
      #pragma unroll
      for (int qs = 0; qs < 2; ++qs) {
        const int qmin = q0 + qw*32 + qs*16;
        const int qgrow = qmin + lr;
        const bool needmask = !((k0 + KBT - 1 <= qmin) && (bm64 == ~0ull));
        float mx = -3.0e38f;
        #pragma unroll
        for (int kt2 = 0; kt2 < 4; ++kt2)
          #pragma unroll
          for (int r = 0; r < 4; ++r) {
            float sv = st[qs][kt2][r];
            if (needmask) {
              const int klo = kt2*16 + kb*4 + r;
              const bool ok = (k0 + klo <= qgrow) && ((bm64 >> klo) & 1ull);
              sv = ok ? sv : -3.0e38f;
              st[qs][kt2][r] = sv;
            }
            mx = fmaxf(mx, sv);
          }
        mx = fmaxf(mx, __shfl_xor(mx, 16));
        mx = fmaxf(mx, __shfl_xor(mx, 32));
        const float mnew = fmaxf(m_run[qs], mx);
        fac[qs] = __builtin_amdgcn_exp2f(m_run[qs] - mnew);
        float lsum = 0.f;
        #pragma unroll
        for (int kt2 = 0; kt2 < 4; ++kt2)
          #pragma unroll
          for (int r = 0; r < 4; ++r) {
            const float pv = __builtin_amdgcn_exp2f(st[qs][kt2][r] - mnew);
            pp[qs][kt2][r] = pv; lsum += pv;
          }
        lsum += __shfl_xor(lsum, 16); lsum += __shfl_xor(lsum, 32);
        l_run[qs] = l_run[qs]*fac[qs] + lsum;
        m_run[qs] = mnew;
      }

      // rescale only when a new max appeared somewhere
      const bool nores = (fac[0] == 1.f) & (fac[1] == 1.f);
      if (!__all(nores)) {
        #pragma unroll
        for (int qs = 0; qs < 2; ++qs) {
          float fq[4];
          #pragma unroll
          for (int r = 0; r < 4; ++r) fq[r] = __shfl(fac[qs], kb*4 + r);
          #pragma unroll
          for (int ct = 0; ct < 16; ++ct) {
            acc[qs][ct][0]*=fq[0]; acc[qs][ct][1]*=fq[1];
            acc[qs][ct][2]*=fq[2]; acc[qs][ct][3]*=fq[3];
          }
        }
      }

      s16x4 pa[2][4];
      #pragma unroll
      for (int qs = 0; qs < 2; ++qs)
        #pragma unroll
        for (int kt2 = 0; kt2 < 4; ++kt2) {
          s16x4 tt = { (short)f2bf(pp[qs][kt2][0]), (short)f2bf(pp[qs][kt2][1]),
                       (short)f2bf(pp[qs][kt2][2]), (short)f2bf(pp[qs][kt2][3]) };
          pa[qs][kt2] = tt;
        }

      // O += P . V256 : one b128 V read feeds 4 MFMAs (2 k-parts x 2 qs)
      const unsigned char* Vc = smem + cur*65536 + 32768;
      #pragma unroll
      for (int ct = 0; ct < 16; ++ct) {
        #pragma unroll
        for (int khalf = 0; khalf < 2; ++khalf) {
          const s16x8 vf = *(const s16x8*)(Vc + ct*2048 + vof0 + khalf*256);
          const s16x4 v0 = { vf[0], vf[1], vf[2], vf[3] };
          const s16x4 v1 = { vf[4], vf[5], vf[6], vf[7] };
          #pragma unroll
          for (int qs = 0; qs < 2; ++qs) {
            acc[qs][ct] = __builtin_amdgcn_mfma_f32_16x16x16bf16_1k(pa[qs][khalf*2+0], v0, acc[qs][ct], 0, 0, 0);
            acc[qs][ct] = __builtin_amdgcn_mfma_f32_16x16x16bf16_1k(pa[qs][khalf*2+1], v1, acc[qs][ct], 0, 0, 0);
          }
        }
      }
      __syncthreads();   // readers done before next prefetch lands; drains vmcnt
    }

    // epilogue: h=1 normalizes into LDS; h=0 combines, RMS-norms, stores
    float lqv[2][4];
    #pragma unroll
    for (int qs = 0; qs < 2; ++qs)
      #pragma unroll
      for (int r = 0; r < 4; ++r) lqv[qs][r] = 1.f / __shfl(l_run[qs], kb*4 + r);
    unsigned char* OB = smem + qw*32768;   // [256 c][128B], chunk ^= (c&7)
    if (h == 1) {
      #pragma unroll
      for (int qs = 0; qs < 2; ++qs)
        #pragma unroll
        for (int ct = 0; ct < 16; ++ct) {
          const int c = ct*16 + lr;
          const int byteo = (qs*64 + kb*16) ^ ((c & 7) << 4);
          f32x4 v = { acc[qs][ct][0]*lqv[qs][0], acc[qs][ct][1]*lqv[qs][1],
                      acc[qs][ct][2]*lqv[qs][2], acc[qs][ct][3]*lqv[qs][3] };
          *(f32x4*)(OB + c*128 + byteo) = v;
        }
    }
    __syncthreads();
    if (h == 0) {
      float ss[2][4] = {{0.f,0.f,0.f,0.f},{0.f,0.f,0.f,0.f}};
      #pragma unroll
      for (int qs = 0; qs < 2; ++qs)
        #pragma unroll
        for (int ct = 0; ct < 16; ++ct) {
          const int c = ct*16 + lr;
          const int byteo = (qs*64 + kb*16) ^ ((c & 7) << 4);
          const f32x4 ob = *(const f32x4*)(OB + c*128 + byteo);
          #pragma unroll
          for (int r = 0; r < 4; ++r) {
            const float v = acc[qs][ct][r]*lqv[qs][r] - lambda_full*ob[r];
            acc[qs][ct][r] = v; ss[qs][r] += v*v;
          }
        }
      #pragma unroll
      for (int o = 8; o; o >>= 1)
        #pragma unroll
        for (int qs = 0; qs < 2; ++qs)
          #pragma unroll
          for (int r = 0; r < 4; ++r) ss[qs][r] += __shfl_xor(ss[qs][r], o);
      const float fin = 1.f - lambda_init;
      float rms[2][4];
      #pragma unroll
      for (int qs = 0; qs < 2; ++qs)
        #pragma unroll
        for (int r = 0; r < 4; ++r)
          rms[qs][r] = rsqrtf(ss[qs][r]*(1.f/256.f) + 1e-5f) * fin;
      #pragma unroll
      for (int qs = 0; qs < 2; ++qs)
        #pragma unroll
        for (int ct = 0; ct < 16; ++ct) {
          const int c = ct*16 + lr;
          const float wv = wsub[c];
          #pragma unroll
          for (int r = 0; r < 4; ++r) {
            const long q = q0 + qw*32 + qs*16 + kb*4 + r;
            outp[(((long)b*SEQ + q)*8 + hp)*256 + c] = acc[qs][ct][r]*rms[qs][r]*wv;
          }
        }
    }
  }
}

extern "C" void kernel_launch(void* const* d_in, const int* in_sizes, int n_in,
                              void* d_out, int out_size, void* d_ws, size_t ws_size,
                              hipStream_t stream) {
  (void)in_sizes; (void)n_in; (void)out_size; (void)ws_size;
  const float lambda_init = (float)(0.8 - 0.6 * exp(-0.3 * (12 - 1)));
  u16* kb16 = (u16*)d_ws;                                 // 16 MB
  u16* vt16 = (u16*)((char*)d_ws + (size_t)16*1024*1024); // 16 MB
  prep_kernel<<<dim3(1024), dim3(256), 0, stream>>>(
      (const float*)d_in[1], (const float*)d_in[2], kb16, vt16);
  diffattn_kernel<<<dim3(256), dim3(256), 0, stream>>>(
      (const float*)d_in[0], kb16, vt16,
      (const float*)d_in[3], (const float*)d_in[4], (const float*)d_in[5],
      (const float*)d_in[6], (const float*)d_in[7],
      (const int*)d_in[8],
      (float*)d_out, lambda_init);
}

// Round 7
// 252.262 us; speedup vs baseline: 1.2712x; 1.2712x over previous
//
#include <hip/hip_runtime.h>
#include <math.h>

namespace {
constexpr int SEQ = 2048;
constexpr int NH  = 16;
constexpr int DH  = 128;
constexpr int QB  = 32;          // q rows per block
constexpr int KBT = 32;          // k rows per iteration

typedef float f32x4 __attribute__((ext_vector_type(4)));
typedef short s16x8 __attribute__((ext_vector_type(8)));
typedef short s16x4 __attribute__((ext_vector_type(4)));
typedef unsigned short u16;

__device__ __forceinline__ u16 f2bf(float f) {
  unsigned u = __builtin_bit_cast(unsigned, f);
  return (u16)((u + 0x7fffu + ((u >> 16) & 1u)) >> 16);
}
__device__ __forceinline__ void gload16(const void* g, void* l) {
  __builtin_amdgcn_global_load_lds((const __attribute__((address_space(1))) void*)g,
                                   (__attribute__((address_space(3))) void*)l, 16, 0, 0);
}
}

// prep: K -> bf16 [b*8+hp][2h][k][128]; V -> bf16 transposed+k-pair-packed
// [b*8+hp][c=256][k']: per 32-k block, slot s (8 u16 at k'=s*8) holds
// k = {s*4+r} U {16+s*4+r}. One block per (b, head, ktile64). (unchanged)
__global__ __launch_bounds__(256) void prep_kernel(
    const float* __restrict__ kgl, const float* __restrict__ vg,
    u16* __restrict__ kb16, u16* __restrict__ vt16)
{
  __shared__ u16 vlds[64][132];
  const int tid = threadIdx.x, bid = blockIdx.x;
  const int kt = bid & 31, head = (bid >> 5) & 15, b = bid >> 9;
  const int k0 = kt * 64, hp = head >> 1, hh = head & 1;
  const float* ksrc = kgl + (((long)b*SEQ + k0)*NH + head)*DH;
  const float* vsrc = vg  + (((long)b*SEQ + k0)*NH + head)*DH;
  u16* kdst = kb16 + (((long)((b*8+hp)*2 + hh)*SEQ) + k0)*DH;
  #pragma unroll
  for (int i = 0; i < 8; ++i) {
    const int idx = tid + i*256, row = idx >> 5, c4 = idx & 31;
    const float4 v = *(const float4*)(ksrc + (long)row*(NH*DH) + c4*4);
    ushort4 pk = { f2bf(v.x), f2bf(v.y), f2bf(v.z), f2bf(v.w) };
    *(ushort4*)(kdst + row*DH + c4*4) = pk;
    const float4 w = *(const float4*)(vsrc + (long)row*(NH*DH) + c4*4);
    ushort4 pw = { f2bf(w.x), f2bf(w.y), f2bf(w.z), f2bf(w.w) };
    *(ushort4*)(&vlds[row][c4*4]) = pw;
  }
  __syncthreads();
  const int c = tid >> 1, half = tid & 1;
  u16* vdst = vt16 + (((long)(b*8+hp)*256) + hh*128 + c)*SEQ + k0 + half*32;
  #pragma unroll
  for (int j = 0; j < 8; ++j) {
    const int kb0 = (j >> 1)*4 + (j & 1)*16;
    ushort4 pk = { vlds[half*32 + kb0 + 0][c], vlds[half*32 + kb0 + 1][c],
                   vlds[half*32 + kb0 + 2][c], vlds[half*32 + kb0 + 3][c] };
    *(ushort4*)(vdst + j*4) = pk;
  }
}

// main: 512 blocks = (hp, b, p in 0..31). Block runs qtile p then 63-p at
// QB=32 -> exactly 65 tile-iters each; 64KB LDS -> 2 independent blocks/CU
// -> 2 waves/SIMD latency hiding. 4 waves = (h, qt), wave owns 16 q-rows.
// LDS buf s @ s*32768: K [2h][32][256B] (chunk^=(row&7));
//                      V @+16384 [64 R][16 ch], ch=(csub<<2)|(slot^(R&3)).
__global__ __launch_bounds__(256, 2) void diffattn_kernel(
    const float* __restrict__ qg,
    const u16* __restrict__ kb16, const u16* __restrict__ vt16,
    const float* __restrict__ lq1, const float* __restrict__ lk1,
    const float* __restrict__ lq2, const float* __restrict__ lk2,
    const float* __restrict__ wsub, const int* __restrict__ amask,
    float* __restrict__ outp, float lambda_init)
{
  __shared__ __align__(16) unsigned char smem[65536];
  const int tid = threadIdx.x, lane = tid & 63, wid = tid >> 6;
  const int h = wid >> 1, qt = wid & 1, lr = lane & 15, kb = lane >> 4;
  const int bid = blockIdx.x;
  const int hp = bid & 7, b = (bid >> 3) & 1, p = bid >> 4;   // p in 0..31

  float s1 = lq1[lane]*lk1[lane] + lq1[lane+64]*lk1[lane+64];
  float s2 = lq2[lane]*lk2[lane] + lq2[lane+64]*lk2[lane+64];
  #pragma unroll
  for (int o = 32; o; o >>= 1) { s1 += __shfl_xor(s1, o); s2 += __shfl_xor(s2, o); }
  const float lambda_full = expf(s1) - expf(s2) + lambda_init;

  // staging source offsets (u16 units); swizzle pre-applied to global source
  int koff[4], voff[4];
  #pragma unroll
  for (int i = 0; i < 4; ++i) {
    const int cid = tid + i*256;
    { const int hh = cid >> 9, row = (cid >> 4) & 31, ch = cid & 15;
      koff[i] = (hh*SEQ + row)*DH + (ch ^ (row & 7))*8; }
    { const int R = cid >> 4, ch = cid & 15;
      const int c = R*4 + (ch >> 2), sl = (ch & 3) ^ (R & 3);
      voff[i] = c*SEQ + sl*8; }
  }
  const u16* kbB = kb16 + (long)(b*8+hp)*2*SEQ*DH;
  const u16* vtB = vt16 + (long)(b*8+hp)*256*SEQ;

  auto STAGE = [&](int k0s, int s) {
    unsigned char* dK = smem + s*32768;
    unsigned char* dV = dK + 16384;
    const u16* ksrc = kbB + (long)k0s*DH;
    const u16* vsrc = vtB + k0s;
    #pragma unroll
    for (int i = 0; i < 4; ++i) {
      gload16(ksrc + koff[i], dK + (tid + i*256)*16);
      gload16(vsrc + voff[i], dV + (tid + i*256)*16);
    }
  };

  const float qscale = 1.44269504088896f / sqrtf((float)DH);
  const int vof0 = ((lr >> 2) << 8) + ((lr & 3) << 6) + ((kb ^ (lr >> 2)) << 4);
  const int swk = (lr & 7) << 4;

  #pragma unroll 1
  for (int qi = 0; qi < 2; ++qi) {
    const int qtile = qi ? (63 - p) : p;
    const int q0 = qtile * QB;
    __syncthreads();                 // prior epilogue LDS reads done

    s16x8 qf[4];
    {
      const int qrow = q0 + qt*16 + lr;
      const float* qp = qg + (((long)b*SEQ + qrow)*NH + hp*2 + h)*DH;
      #pragma unroll
      for (int ds = 0; ds < 4; ++ds) {
        const float4 a0 = *(const float4*)(qp + ds*32 + kb*8);
        const float4 a1 = *(const float4*)(qp + ds*32 + kb*8 + 4);
        s16x8 f;
        f[0]=(short)f2bf(a0.x*qscale); f[1]=(short)f2bf(a0.y*qscale);
        f[2]=(short)f2bf(a0.z*qscale); f[3]=(short)f2bf(a0.w*qscale);
        f[4]=(short)f2bf(a1.x*qscale); f[5]=(short)f2bf(a1.y*qscale);
        f[6]=(short)f2bf(a1.z*qscale); f[7]=(short)f2bf(a1.w*qscale);
        qf[ds] = f;
      }
    }

    f32x4 acc[16];
    #pragma unroll
    for (int i = 0; i < 16; ++i) acc[i] = (f32x4){0.f,0.f,0.f,0.f};
    float m_run = -3.0e38f, l_run = 0.f;
    const int nt = qtile + 1;
    const int qmin = q0 + qt*16;
    const int qgrow = qmin + lr;

    STAGE(0, 0);
    __syncthreads();                 // buf0 ready (barrier drains vmcnt)

    for (int t = 0; t < nt; ++t) {
      const int cur = t & 1;
      if (t + 1 < nt) STAGE((t+1)*KBT, cur ^ 1);    // async prefetch
      const int k0 = t * KBT;

      const int mi = amask[b*SEQ + k0 + (lane & 31)];
      const unsigned bm32 = (unsigned)__ballot(mi != 0 && lane < 32);

      // S^T = K . Q^T (16x16x32)
      const unsigned char* Kc = smem + cur*32768 + h*8192;
      f32x4 st[2];
      #pragma unroll
      for (int kt2 = 0; kt2 < 2; ++kt2) {
        const unsigned char* kr = Kc + (kt2*16 + lr)*256;
        f32x4 c = {0.f,0.f,0.f,0.f};
        #pragma unroll
        for (int ds = 0; ds < 4; ++ds) {
          const s16x8 af = *(const s16x8*)(kr + ((ds*64 + kb*16) ^ swk));
          c = __builtin_amdgcn_mfma_f32_16x16x32_bf16(af, qf[ds], c, 0, 0, 0);
        }
        st[kt2] = c;
      }

      // online softmax (exp2 domain); lane owns q-row lr, k = kt2*16+kb*4+r
      const bool needmask = !((k0 + KBT - 1 <= qmin) && (bm32 == 0xffffffffu));
      float mx = -3.0e38f;
      float pp[2][4];
      #pragma unroll
      for (int kt2 = 0; kt2 < 2; ++kt2)
        #pragma unroll
        for (int r = 0; r < 4; ++r) {
          float sv = st[kt2][r];
          if (needmask) {
            const int klo = kt2*16 + kb*4 + r;
            const bool ok = (k0 + klo <= qgrow) && ((bm32 >> klo) & 1u);
            sv = ok ? sv : -3.0e38f;
            st[kt2][r] = sv;
          }
          mx = fmaxf(mx, sv);
        }
      mx = fmaxf(mx, __shfl_xor(mx, 16));
      mx = fmaxf(mx, __shfl_xor(mx, 32));

      // T13 defer-max: skip rescale when max grew by <= 8 (exp2 domain);
      // pp then bounded by 2^8 which f32/bf16 handle fine.
      float fac = 1.f;
      if (!__all(mx - m_run <= 8.f)) {
        const float mnew = fmaxf(m_run, mx);
        fac = __builtin_amdgcn_exp2f(m_run - mnew);
        m_run = mnew;
        float fq[4];
        #pragma unroll
        for (int r = 0; r < 4; ++r) fq[r] = __shfl(fac, kb*4 + r);
        #pragma unroll
        for (int ct = 0; ct < 16; ++ct) {
          acc[ct][0]*=fq[0]; acc[ct][1]*=fq[1];
          acc[ct][2]*=fq[2]; acc[ct][3]*=fq[3];
        }
      }
      float lsum = 0.f;
      #pragma unroll
      for (int kt2 = 0; kt2 < 2; ++kt2)
        #pragma unroll
        for (int r = 0; r < 4; ++r) {
          const float pv = __builtin_amdgcn_exp2f(st[kt2][r] - m_run);
          pp[kt2][r] = pv; lsum += pv;
        }
      lsum += __shfl_xor(lsum, 16); lsum += __shfl_xor(lsum, 32);
      l_run = l_run*fac + lsum;

      s16x4 pa[2];
      #pragma unroll
      for (int kt2 = 0; kt2 < 2; ++kt2) {
        s16x4 tt = { (short)f2bf(pp[kt2][0]), (short)f2bf(pp[kt2][1]),
                     (short)f2bf(pp[kt2][2]), (short)f2bf(pp[kt2][3]) };
        pa[kt2] = tt;
      }

      // O += P . V256 : one b128 V read feeds 2 MFMAs (k-pair packing)
      const unsigned char* Vc = smem + cur*32768 + 16384;
      #pragma unroll
      for (int ct = 0; ct < 16; ++ct) {
        const s16x8 vf = *(const s16x8*)(Vc + ct*1024 + vof0);
        const s16x4 v0 = { vf[0], vf[1], vf[2], vf[3] };
        const s16x4 v1 = { vf[4], vf[5], vf[6], vf[7] };
        acc[ct] = __builtin_amdgcn_mfma_f32_16x16x16bf16_1k(pa[0], v0, acc[ct], 0, 0, 0);
        acc[ct] = __builtin_amdgcn_mfma_f32_16x16x16bf16_1k(pa[1], v1, acc[ct], 0, 0, 0);
      }
      __syncthreads();   // readers done before next prefetch lands; drains vmcnt
    }

    // epilogue: h=1 normalizes into OB (aliases buf0, 32KB); h=0 combines,
    // RMS-norms, stores. Chunk-swizzled OB: [256 c][32 f32], chunk ^= (c&7).
    float lqv[4];
    #pragma unroll
    for (int r = 0; r < 4; ++r) lqv[r] = 1.f / __shfl(l_run, kb*4 + r);
    unsigned char* OB = smem;
    if (h == 1) {
      #pragma unroll
      for (int ct = 0; ct < 16; ++ct) {
        const int c = ct*16 + lr;
        const int byteo = (qt*64 + kb*16) ^ ((c & 7) << 4);
        f32x4 v = { acc[ct][0]*lqv[0], acc[ct][1]*lqv[1],
                    acc[ct][2]*lqv[2], acc[ct][3]*lqv[3] };
        *(f32x4*)(OB + c*128 + byteo) = v;
      }
    }
    __syncthreads();
    if (h == 0) {
      float ss[4] = {0.f,0.f,0.f,0.f};
      #pragma unroll
      for (int ct = 0; ct < 16; ++ct) {
        const int c = ct*16 + lr;
        const int byteo = (qt*64 + kb*16) ^ ((c & 7) << 4);
        const f32x4 ob = *(const f32x4*)(OB + c*128 + byteo);
        #pragma unroll
        for (int r = 0; r < 4; ++r) {
          const float v = acc[ct][r]*lqv[r] - lambda_full*ob[r];
          acc[ct][r] = v; ss[r] += v*v;
        }
      }
      #pragma unroll
      for (int o = 8; o; o >>= 1)
        #pragma unroll
        for (int r = 0; r < 4; ++r) ss[r] += __shfl_xor(ss[r], o);
      const float fin = 1.f - lambda_init;
      float rms[4];
      #pragma unroll
      for (int r = 0; r < 4; ++r) rms[r] = rsqrtf(ss[r]*(1.f/256.f) + 1e-5f) * fin;
      #pragma unroll
      for (int ct = 0; ct < 16; ++ct) {
        const int c = ct*16 + lr;
        const float wv = wsub[c];
        #pragma unroll
        for (int r = 0; r < 4; ++r) {
          const long q = q0 + qt*16 + kb*4 + r;
          outp[(((long)b*SEQ + q)*8 + hp)*256 + c] = acc[ct][r]*rms[r]*wv;
        }
      }
    }
  }
}

extern "C" void kernel_launch(void* const* d_in, const int* in_sizes, int n_in,
                              void* d_out, int out_size, void* d_ws, size_t ws_size,
                              hipStream_t stream) {
  (void)in_sizes; (void)n_in; (void)out_size; (void)ws_size;
  const float lambda_init = (float)(0.8 - 0.6 * exp(-0.3 * (12 - 1)));
  u16* kb16 = (u16*)d_ws;                                 // 16 MB
  u16* vt16 = (u16*)((char*)d_ws + (size_t)16*1024*1024); // 16 MB
  prep_kernel<<<dim3(1024), dim3(256), 0, stream>>>(
      (const float*)d_in[1], (const float*)d_in[2], kb16, vt16);
  diffattn_kernel<<<dim3(512), dim3(256), 0, stream>>>(
      (const float*)d_in[0], kb16, vt16,
      (const float*)d_in[3], (const float*)d_in[4], (const float*)d_in[5],
      (const float*)d_in[6], (const float*)d_in[7],
      (const int*)d_in[8],
      (float*)d_out, lambda_init);
}